// Round 12
// baseline (118.389 us; speedup 1.0000x reference)
//
#include <hip/hip_runtime.h>
#include <math.h>

#define NB 2
#define NN 4096
#define NK 512
#define NC 384
#define NR 16
#define NSLICE 64

static constexpr float INV_SQRT_C = 0.051031036307982884f; // 1/sqrt(384)
static constexpr float TWO_PI     = 6.283185307179586f;
static constexpr float F_JITTER   = 1e-4f;

typedef __attribute__((ext_vector_type(8))) short short8;
typedef __attribute__((ext_vector_type(4))) float f32x4;
typedef __attribute__((ext_vector_type(4))) unsigned short us4;
typedef __attribute__((ext_vector_type(8))) unsigned short us8;

__device__ __forceinline__ void split3(float x, unsigned short& h, unsigned short& m_, unsigned short& l_) {
    unsigned int xi = __float_as_uint(x);
    unsigned int uh = (xi + 0x7fffu + ((xi >> 16) & 1u)) >> 16;
    float fh = __uint_as_float(uh << 16);
    float r  = x - fh;
    unsigned int ri = __float_as_uint(r);
    unsigned int um = (ri + 0x7fffu + ((ri >> 16) & 1u)) >> 16;
    float fm = __uint_as_float(um << 16);
    float r2 = r - fm;
    unsigned int r2i = __float_as_uint(r2);
    unsigned int ul = (r2i + 0x7fffu + ((r2i >> 16) & 1u)) >> 16;
    h = (unsigned short)uh; m_ = (unsigned short)um; l_ = (unsigned short)ul;
}

// ======== launch 1: blocks 0..1 masksum | blocks 2..37 W2 = Wk @ Wq^T ========
__global__ __launch_bounds__(256) void k_pre(const float* __restrict__ node_mask,
                                             const float* __restrict__ Wk,
                                             const float* __restrict__ Wq,
                                             float* __restrict__ Lsum,
                                             float* __restrict__ W2) {
    __shared__ float red[256];
    __shared__ float As[16][68];
    __shared__ float Ws[16][68];
    int bid = blockIdx.x, t = threadIdx.x;
    if (bid < 2) {
        int b = bid;
        float s = 0.f;
        for (int n = t; n < NN; n += 256) s += node_mask[b*NN + n];
        red[t] = s; __syncthreads();
        for (int w = 128; w > 0; w >>= 1) { if (t < w) red[t] += red[t+w]; __syncthreads(); }
        if (t == 0) Lsum[b] = red[0];
        return;
    }
    int gb = bid - 2;
    int rowbase = (gb % 6) * 64, colbase = (gb / 6) * 64;
    int tx = t & 15, ty = t >> 4;
    float acc[4][4] = {};
    for (int k0 = 0; k0 < NC; k0 += 16) {
        {
            int r = t >> 2, ja = (t & 3) << 2;
            float4 a4 = *(const float4*)(Wk + (size_t)(rowbase + r)*NC + k0 + ja);
            As[ja+0][r] = a4.x; As[ja+1][r] = a4.y; As[ja+2][r] = a4.z; As[ja+3][r] = a4.w;
        }
        {
            int r = t >> 2, jb = (t & 3) << 2;
            float4 b4 = *(const float4*)(Wq + (size_t)(colbase + r)*NC + k0 + jb);
            Ws[jb+0][r] = b4.x; Ws[jb+1][r] = b4.y; Ws[jb+2][r] = b4.z; Ws[jb+3][r] = b4.w;
        }
        __syncthreads();
        #pragma unroll
        for (int kk = 0; kk < 16; ++kk) {
            float4 av = *(const float4*)&As[kk][ty<<2];
            float4 wv = *(const float4*)&Ws[kk][tx<<2];
            float aa[4] = {av.x, av.y, av.z, av.w};
            float ww[4] = {wv.x, wv.y, wv.z, wv.w};
            #pragma unroll
            for (int i = 0; i < 4; ++i)
                #pragma unroll
                for (int j = 0; j < 4; ++j)
                    acc[i][j] += aa[i]*ww[j];
        }
        __syncthreads();
    }
    #pragma unroll
    for (int i = 0; i < 4; ++i) {
        float4 o = make_float4(acc[i][0], acc[i][1], acc[i][2], acc[i][3]);
        *(float4*)(W2 + (size_t)(rowbase + (ty<<2) + i)*NC + colbase + (tx<<2)) = o;
    }
}

// ======== launch 2: [0,192) dualz GEMM | [192,448) topk | [448,2496) q0  + occ zero ========
template<bool SPLIT>
__global__ __launch_bounds__(256) void k_mid(const float* __restrict__ s_parent,
                                             const float* __restrict__ Wv,
                                             const float* __restrict__ W2,
                                             const int* __restrict__ res_idx,
                                             const float* __restrict__ node_mask,
                                             const float* __restrict__ Bm,
                                             const float* __restrict__ ln_g,
                                             const float* __restrict__ ln_b,
                                             const float* __restrict__ Lsum,
                                             const float* __restrict__ mu,
                                             const float* __restrict__ Sg,
                                             const float* __restrict__ maskp,
                                             float* __restrict__ vmat,
                                             float* __restrict__ GtF,
                                             unsigned short* __restrict__ gh,
                                             unsigned short* __restrict__ gm,
                                             unsigned short* __restrict__ gl,
                                             float* __restrict__ q0f,
                                             unsigned short* __restrict__ qh,
                                             unsigned short* __restrict__ qm,
                                             unsigned short* __restrict__ ql,
                                             int* __restrict__ knn,
                                             float* __restrict__ occ_part) {
    __shared__ float As[16][68];
    __shared__ float Ws[16][68];
    int bid = blockIdx.x, t = threadIdx.x;

    if (bid < 256) {                // zero occ_part [64][1024] = 65536 floats (precedes k_fused atomics)
        occ_part[bid*256 + t] = 0.f;
    }

    if (bid < 192) {                // ---- dual-z GEMM: z=0 vmat=s@Wv, z=1 Gt=s@W2 ----
        int z = bid / 96, rem = bid % 96;
        int rowbase = (rem % 16) * 64, colbase = (rem / 16) * 64;
        const float* W = z ? W2 : Wv;
        int tx = t & 15, ty = t >> 4;
        float acc[4][4] = {};
        for (int k0 = 0; k0 < NC; k0 += 16) {
            {
                int r = t >> 2, ja = (t & 3) << 2;
                float4 a4 = *(const float4*)(s_parent + (size_t)(rowbase + r)*NC + k0 + ja);
                As[ja+0][r] = a4.x; As[ja+1][r] = a4.y; As[ja+2][r] = a4.z; As[ja+3][r] = a4.w;
            }
            {
                int kr = t >> 4, jw = (t & 15) << 2;
                float4 w4 = *(const float4*)(W + (size_t)(k0 + kr)*NC + colbase + jw);
                *(float4*)&Ws[kr][jw] = w4;
            }
            __syncthreads();
            #pragma unroll
            for (int kk = 0; kk < 16; ++kk) {
                float4 av = *(const float4*)&As[kk][ty<<2];
                float4 wv = *(const float4*)&Ws[kk][tx<<2];
                float aa[4] = {av.x, av.y, av.z, av.w};
                float ww[4] = {wv.x, wv.y, wv.z, wv.w};
                #pragma unroll
                for (int i = 0; i < 4; ++i)
                    #pragma unroll
                    for (int j = 0; j < 4; ++j)
                        acc[i][j] += aa[i]*ww[j];
            }
            __syncthreads();
        }
        #pragma unroll
        for (int i = 0; i < 4; ++i) {
            size_t ro = (size_t)(rowbase + (ty<<2) + i)*NC + colbase + (tx<<2);
            if (z == 0) {
                *(float4*)(vmat + ro) = make_float4(acc[i][0], acc[i][1], acc[i][2], acc[i][3]);
            } else if constexpr (SPLIT) {
                us4 vh, vm, vl;
                #pragma unroll
                for (int j = 0; j < 4; ++j) {
                    unsigned short h, mm, ll;
                    split3(acc[i][j], h, mm, ll);
                    vh[j] = h; vm[j] = mm; vl[j] = ll;
                }
                *(us4*)(gh + ro) = vh; *(us4*)(gm + ro) = vm; *(us4*)(gl + ro) = vl;
            } else {
                *(float4*)(GtF + ro) = make_float4(acc[i][0], acc[i][1], acc[i][2], acc[i][3]);
            }
        }
        return;
    }

    if (bid < 448) {                // ---- topk: one 64-lane wave per row ----
        int wv_ = t >> 6, lane = t & 63;
        int tb = ((bid - 192) << 2) + wv_;
        int b = tb >> 9, i = tb & 511;
        const float* mui = mu + (size_t)(b*NK + i)*3;
        const float* Sgi = Sg + (size_t)(b*NK + i)*9;
        float mi0 = mui[0], mi1 = mui[1], mi2 = mui[2];
        float S0 = Sgi[0], S1 = Sgi[1], S2 = Sgi[2], S4 = Sgi[4], S5 = Sgi[5], S8 = Sgi[8];
        float mski = maskp[b*NK + i];
        float cand[8];
        #pragma unroll
        for (int h = 0; h < 8; ++h) {
            int j = lane + (h << 6);
            const float* muj = mu + (size_t)(b*NK + j)*3;
            const float* Sgj = Sg + (size_t)(b*NK + j)*9;
            float d0 = mi0-muj[0], d1 = mi1-muj[1], d2 = mi2-muj[2];
            float a00 = S0+Sgj[0]+1e-6f, a01 = S1+Sgj[1],       a02 = S2+Sgj[2];
            float a11 = S4+Sgj[4]+1e-6f, a12 = S5+Sgj[5],       a22 = S8+Sgj[8]+1e-6f;
            float c00 = a11*a22 - a12*a12;
            float c01 = a02*a12 - a01*a22;
            float c02 = a01*a12 - a02*a11;
            float c11 = a00*a22 - a02*a02;
            float c12 = a01*a02 - a00*a12;
            float c22 = a00*a11 - a01*a01;
            float det = a00*c00 + a01*c01 + a02*c02;
            float t0 = c00*d0 + c01*d1 + c02*d2;
            float t1 = c01*d0 + c11*d1 + c12*d2;
            float t2 = c02*d0 + c12*d1 + c22*d2;
            float maha = (d0*t0 + d1*t1 + d2*t2) / det;
            float score = -0.5f*(maha + logf(det));
            float mj = maskp[b*NK + j];
            cand[h] = (mski*mj < 0.5f) ? -1e9f : score;
        }
        for (int it = 0; it < NR; ++it) {
            float bv = cand[0]; int bh = 0;
            #pragma unroll
            for (int h = 1; h < 8; ++h)
                if (cand[h] > bv) { bv = cand[h]; bh = h; }
            int bi = lane + (bh << 6);
            #pragma unroll
            for (int off = 32; off > 0; off >>= 1) {
                float v2 = __shfl_xor(bv, off);
                int   i2 = __shfl_xor(bi, off);
                if (v2 > bv || (v2 == bv && i2 < bi)) { bv = v2; bi = i2; }
            }
            if (lane == 0) knn[((size_t)(b*NK + i))*NR + it] = bi;
            if ((bi & 63) == lane) {
                int s = bi >> 6;
                #pragma unroll
                for (int h = 0; h < 8; ++h)
                    if (h == s) cand[h] = -INFINITY;
            }
        }
        return;
    }

    // ---- q0: fourier emb + layernorm, wave-per-row ----
    int q0b = bid - 448;
    int w = t >> 6, l = t & 63;
    int row = (q0b << 2) + w;
    int b = row >> 12;
    float m = node_mask[row];
    float Lb = fmaxf(Lsum[b], 1.0f);
    float denom = fmaxf(Lb - 1.0f, 1.0f);
    int ri = res_idx[row];
    ri = ri < 0 ? 0 : (ri > 4095 ? 4095 : ri);
    float pos = fminf(fmaxf((float)ri / denom, 0.f), 1.f);
    float v[6];
    #pragma unroll
    for (int j = 0; j < 3; ++j) {
        float pr = TWO_PI * pos * Bm[l + (j << 6)];
        v[j]   = cosf(pr) * m;
        v[j+3] = sinf(pr) * m;
    }
    float sum = v[0]+v[1]+v[2]+v[3]+v[4]+v[5];
    #pragma unroll
    for (int off = 32; off > 0; off >>= 1) sum += __shfl_xor(sum, off);
    float mean = sum * (1.0f/NC);
    float sq = 0.f;
    #pragma unroll
    for (int j = 0; j < 6; ++j) { v[j] -= mean; sq += v[j]*v[j]; }
    #pragma unroll
    for (int off = 32; off > 0; off >>= 1) sq += __shfl_xor(sq, off);
    float var = sq * (1.0f/NC);
    float inv = 1.0f / sqrtf(var + 1e-5f);
    #pragma unroll
    for (int j = 0; j < 6; ++j) {
        int p = l + (j << 6);
        float val = v[j]*inv*ln_g[p] + ln_b[p];
        size_t o = (size_t)row*NC + p;
        if constexpr (SPLIT) {
            unsigned short h, mm, ll;
            split3(val, h, mm, ll);
            qh[o] = h; qm[o] = mm; ql[o] = ll;
        } else {
            q0f[o] = val;
        }
    }
}

// ======== launch 3: FUSED logits (32 rows x 512 cols, B direct from L2, no B-staging) ========
template<bool SPLIT>
__global__ __launch_bounds__(256) void k_fused(const float* __restrict__ q0f,
                                               const unsigned short* __restrict__ qh,
                                               const unsigned short* __restrict__ qm,
                                               const unsigned short* __restrict__ ql,
                                               const float* __restrict__ GtF,
                                               const unsigned short* __restrict__ gh,
                                               const unsigned short* __restrict__ gm,
                                               const unsigned short* __restrict__ gl,
                                               const float* __restrict__ maskp,
                                               const float* __restrict__ vmat,
                                               const float* __restrict__ mu,
                                               const float* __restrict__ Sg,
                                               const float* __restrict__ node_mask,
                                               const int* __restrict__ knn,
                                               float* __restrict__ out_s0,
                                               float* __restrict__ out_mu0,
                                               float* __restrict__ out_Sig0,
                                               float* __restrict__ out_Bl,
                                               float* __restrict__ occ_part,
                                               float* __restrict__ loss_part) {
    int bid = blockIdx.x, t = threadIdx.x;
    int grow0 = bid << 5;               // 32 global rows per block
    int b = grow0 >> 12;

    __shared__ __align__(16) unsigned short Ah[32][40];
    __shared__ __align__(16) unsigned short Am[32][40];
    __shared__ __align__(16) unsigned short Al[32][40];
    __shared__ float lgs[32][516];
    __shared__ float rmv[32][4];
    __shared__ int   rmi[32][4];
    __shared__ int   j0s[32];
    __shared__ float wl[32][17];
    __shared__ int   pidx[32][17];
    __shared__ float lred[32];
    __shared__ float msk[32];

    int lane = t & 63, wv = t >> 6;
    int a = lane & 15, g = lane >> 4;

    f32x4 acc[2][8];
    #pragma unroll
    for (int i = 0; i < 2; ++i)
        #pragma unroll
        for (int j = 0; j < 8; ++j)
            acc[i][j] = (f32x4){0.f, 0.f, 0.f, 0.f};

    const size_t browB = (size_t)(b << 9);     // Gt row base for this batch

    for (int k0 = 0; k0 < NC; k0 += 32) {
        __syncthreads();
        if constexpr (SPLIT) {
            if (t < 128) {                      // A: 32 rows x 4 us8-segs
                int row = t >> 2, s2 = t & 3;
                size_t go = (size_t)(grow0 + row)*NC + k0 + (s2 << 3);
                *(us8*)&Ah[row][s2 << 3] = *(const us8*)(qh + go);
                *(us8*)&Am[row][s2 << 3] = *(const us8*)(qm + go);
                *(us8*)&Al[row][s2 << 3] = *(const us8*)(ql + go);
            }
        } else {
            {                                   // A: 32 rows x 8 f4-segs = 256 tasks
                int row = t >> 3, seg = t & 7;
                float4 v = *(const float4*)(q0f + (size_t)(grow0 + row)*NC + k0 + (seg << 2));
                unsigned short h0,m0,l0,h1,m1,l1,h2,m2,l2,h3,m3,l3;
                split3(v.x, h0, m0, l0); split3(v.y, h1, m1, l1);
                split3(v.z, h2, m2, l2); split3(v.w, h3, m3, l3);
                *(us4*)&Ah[row][seg << 2] = (us4){h0, h1, h2, h3};
                *(us4*)&Am[row][seg << 2] = (us4){m0, m1, m2, m3};
                *(us4*)&Al[row][seg << 2] = (us4){l0, l1, l2, l3};
            }
        }
        __syncthreads();
        short8 afh[2], afm[2], afl[2];
        #pragma unroll
        for (int fr = 0; fr < 2; ++fr) {
            int r = (fr << 4) + a;
            afh[fr] = *(const short8*)&Ah[r][g << 3];
            afm[fr] = *(const short8*)&Am[r][g << 3];
            afl[fr] = *(const short8*)&Al[r][g << 3];
        }
        #pragma unroll
        for (int fc = 0; fc < 8; ++fc) {
            int c = (wv << 7) + (fc << 4) + a;
            size_t go = (browB + c)*NC + k0 + (g << 3);
            short8 bh, bm, bl;
            if constexpr (SPLIT) {
                bh = *(const short8*)(gh + go);
                bm = *(const short8*)(gm + go);
                bl = *(const short8*)(gl + go);
            } else {
                float4 v0 = *(const float4*)(GtF + go);
                float4 v1 = *(const float4*)(GtF + go + 4);
                float vv[8] = {v0.x, v0.y, v0.z, v0.w, v1.x, v1.y, v1.z, v1.w};
                #pragma unroll
                for (int e = 0; e < 8; ++e) {
                    unsigned short h, mm2, ll2;
                    split3(vv[e], h, mm2, ll2);
                    bh[e] = (short)h; bm[e] = (short)mm2; bl[e] = (short)ll2;
                }
            }
            #pragma unroll
            for (int fr = 0; fr < 2; ++fr) {
                acc[fr][fc] = __builtin_amdgcn_mfma_f32_16x16x32_bf16(afh[fr], bh, acc[fr][fc], 0, 0, 0);
                acc[fr][fc] = __builtin_amdgcn_mfma_f32_16x16x32_bf16(afh[fr], bm, acc[fr][fc], 0, 0, 0);
                acc[fr][fc] = __builtin_amdgcn_mfma_f32_16x16x32_bf16(afm[fr], bh, acc[fr][fc], 0, 0, 0);
                acc[fr][fc] = __builtin_amdgcn_mfma_f32_16x16x32_bf16(afh[fr], bl, acc[fr][fc], 0, 0, 0);
                acc[fr][fc] = __builtin_amdgcn_mfma_f32_16x16x32_bf16(afl[fr], bh, acc[fr][fc], 0, 0, 0);
                acc[fr][fc] = __builtin_amdgcn_mfma_f32_16x16x32_bf16(afm[fr], bm, acc[fr][fc], 0, 0, 0);
            }
        }
    }
    __syncthreads();

    float mk[8];
    #pragma unroll
    for (int fc = 0; fc < 8; ++fc)
        mk[fc] = (maskp[(b << 9) + (wv << 7) + (fc << 4) + a] - 1.0f) * 1e9f;
    #pragma unroll
    for (int fr = 0; fr < 2; ++fr) {
        #pragma unroll
        for (int reg = 0; reg < 4; ++reg) {
            int row = (fr << 4) + (g << 2) + reg;
            float bv = -INFINITY; int bc = 0;
            #pragma unroll
            for (int fc = 0; fc < 8; ++fc) {      // ascending col per lane: strict > keeps first
                int col = (wv << 7) + (fc << 4) + a;
                float v = acc[fr][fc][reg] * INV_SQRT_C;
                lgs[row][col] = v;
                float w1 = v + mk[fc];
                if (w1 > bv) { bv = w1; bc = col; }
            }
            #pragma unroll
            for (int off = 1; off < 16; off <<= 1) {
                float v2 = __shfl_xor(bv, off);
                int   c2 = __shfl_xor(bc, off);
                if (v2 > bv || (v2 == bv && c2 < bc)) { bv = v2; bc = c2; }
            }
            if (a == 0) { rmv[row][wv] = bv; rmi[row][wv] = bc; }
        }
    }
    __syncthreads();
    if (t < 32) {                                 // combine 4 waves -> j0
        float bv = rmv[t][0]; int bc = rmi[t][0];
        #pragma unroll
        for (int w2 = 1; w2 < 4; ++w2) {
            float v2 = rmv[t][w2]; int c2 = rmi[t][w2];
            if (v2 > bv || (v2 == bv && c2 < bc)) { bv = v2; bc = c2; }
        }
        j0s[t] = bc;
    }
    __syncthreads();

    // epilogue: 16 groups of 16 lanes, 2 rows each
    int grp = t >> 4, ll = t & 15;
    #pragma unroll
    for (int rr2 = 0; rr2 < 2; ++rr2) {
        int r = (grp << 1) + rr2;
        int growr = grow0 + r;
        float m = node_mask[growr];
        int p = knn[((size_t)(b*NK + j0s[r]))*NR + ll];
        float v = lgs[r][p];
        float mx = v;
        #pragma unroll
        for (int off = 8; off > 0; off >>= 1) mx = fmaxf(mx, __shfl_xor(mx, off));
        float e = expf(v - mx);
        float sme = e;
        #pragma unroll
        for (int off = 8; off > 0; off >>= 1) sme += __shfl_xor(sme, off);
        float w = e / sme;
        wl[r][ll] = w;
        pidx[r][ll] = p;
        out_Bl[(size_t)growr*NR + ll] = w;

        const float* mur = mu + (size_t)(b*NK + p)*3;
        const float* Sgr = Sg + (size_t)(b*NK + p)*9;
        float mr0 = mur[0], mr1 = mur[1], mr2 = mur[2];
        float m0 = w*mr0, m1 = w*mr1, m2 = w*mr2;
        #pragma unroll
        for (int off = 8; off > 0; off >>= 1) {
            m0 += __shfl_xor(m0, off); m1 += __shfl_xor(m1, off); m2 += __shfl_xor(m2, off);
        }
        float d0 = mr0-m0, d1 = mr1-m1, d2 = mr2-m2;
        float a00 = Sgr[0], a01 = Sgr[1], a02 = Sgr[2];
        float a11 = Sgr[4], a12 = Sgr[5], a22 = Sgr[8];
        float p00 = w*(a00 + d0*d0), p01 = w*(a01 + d0*d1), p02 = w*(a02 + d0*d2);
        float p11 = w*(a11 + d1*d1), p12 = w*(a12 + d1*d2), p22 = w*(a22 + d2*d2);
        #pragma unroll
        for (int off = 8; off > 0; off >>= 1) {
            p00 += __shfl_xor(p00, off); p01 += __shfl_xor(p01, off); p02 += __shfl_xor(p02, off);
            p11 += __shfl_xor(p11, off); p12 += __shfl_xor(p12, off); p22 += __shfl_xor(p22, off);
        }
        float c00 = a11*a22 - a12*a12;
        float c01 = a02*a12 - a01*a22;
        float c02 = a01*a12 - a02*a11;
        float c11 = a00*a22 - a02*a02;
        float c12 = a01*a02 - a00*a12;
        float c22 = a00*a11 - a01*a01;
        float det = a00*c00 + a01*c01 + a02*c02;
        float t0 = c00*d0 + c01*d1 + c02*d2;
        float t1 = c01*d0 + c11*d1 + c12*d2;
        float t2 = c02*d0 + c12*d1 + c22*d2;
        float maha = (d0*t0 + d1*t1 + d2*t2) / det;
        float score = -0.5f*(maha + logf(det));
        float lp = w*score;
        #pragma unroll
        for (int off = 8; off > 0; off >>= 1) lp += __shfl_xor(lp, off);
        if (ll == 0) {
            out_mu0[(size_t)growr*3+0] = m0;
            out_mu0[(size_t)growr*3+1] = m1;
            out_mu0[(size_t)growr*3+2] = m2;
            float* o = out_Sig0 + (size_t)growr*9;
            o[0]=p00+F_JITTER; o[1]=p01;          o[2]=p02;
            o[3]=p01;          o[4]=p11+F_JITTER; o[5]=p12;
            o[6]=p02;          o[7]=p12;          o[8]=p22+F_JITTER;
            lred[r] = m*lp;
            msk[r] = m;
        }
        atomicAdd(&occ_part[(size_t)(bid & (NSLICE-1))*(NB*NK) + b*NK + p], w*m);
    }
    __syncthreads();
    if (t == 0) {
        float s = 0.f;
        #pragma unroll
        for (int i = 0; i < 32; ++i) s += lred[i];
        loss_part[bid] = s;
    }
    // PV: 32 rows x 96 float4 = 3072 tasks over 256 threads (12 iters)
    const float4* vb = (const float4*)(vmat + (size_t)b*NK*NC);
    #pragma unroll
    for (int it = 0; it < 12; ++it) {
        int id = it*256 + t;
        int row = id / 96;
        int col = id - row*96;
        float4 acc4 = make_float4(0.f, 0.f, 0.f, 0.f);
        #pragma unroll
        for (int r2 = 0; r2 < NR; ++r2) {
            float ww = wl[row][r2];
            float4 vv = vb[(size_t)pidx[row][r2]*96 + col];
            acc4.x += ww*vv.x; acc4.y += ww*vv.y; acc4.z += ww*vv.z; acc4.w += ww*vv.w;
        }
        float mm = msk[row];
        acc4.x *= mm; acc4.y *= mm; acc4.z *= mm; acc4.w *= mm;
        ((float4*)(out_s0 + (size_t)(grow0 + row)*NC))[col] = acc4;
    }
}

// ======== launch 4: occ-slice reduce + normalize + loss (2 blocks) ========
__global__ __launch_bounds__(512) void k_finalize(const float* __restrict__ occ_part,
                                                  const float* __restrict__ Lsum,
                                                  const float* __restrict__ loss_part,
                                                  float* __restrict__ out_occn,
                                                  float* __restrict__ out_loss) {
    int b = blockIdx.x, t = threadIdx.x;
    __shared__ float red[512];
    float s = 0.f;
    for (int sl = 0; sl < NSLICE; ++sl) s += occ_part[(size_t)sl*(NB*NK) + b*NK + t];
    red[t] = s; __syncthreads();
    for (int w = 256; w > 0; w >>= 1) { if (t < w) red[t] += red[t+w]; __syncthreads(); }
    float tot = red[0];
    __syncthreads();
    out_occn[b*NK + t] = s / fmaxf(tot, 1e-9f);
    if (b == 0) {
        red[t] = (t < 256) ? loss_part[t] : 0.f;
        __syncthreads();
        for (int w = 256; w > 0; w >>= 1) { if (t < w) red[t] += red[t+w]; __syncthreads(); }
        if (t == 0) {
            float dnm = fmaxf(Lsum[0] + Lsum[1], 1.0f);
            out_loss[0] = -(red[0] / dnm);
        }
    }
}

extern "C" void kernel_launch(void* const* d_in, const int* in_sizes, int n_in,
                              void* d_out, int out_size, void* d_ws, size_t ws_size,
                              hipStream_t stream) {
    const float* s_parent   = (const float*)d_in[0];
    const float* mu_parent  = (const float*)d_in[1];
    const float* Sig_parent = (const float*)d_in[2];
    const float* mask_par   = (const float*)d_in[3];
    const float* node_mask  = (const float*)d_in[4];
    const int*   res_idx    = (const int*)d_in[5];
    const float* Bm         = (const float*)d_in[6];
    const float* Wq         = (const float*)d_in[7];
    const float* Wk         = (const float*)d_in[8];
    const float* Wv         = (const float*)d_in[9];
    const float* ln_g       = (const float*)d_in[10];
    const float* ln_b       = (const float*)d_in[11];

    const bool G = (ws_size >= (43ull << 20));   // pre-split path; fallback = fp32+in-kernel split

    float* ws = (float*)d_ws;
    const size_t SZ_A    = G ? 4718592 : 3145728;
    const size_t OFF_LOG = 0;                            // layout kept from proven rounds
    const size_t OFF_A   = OFF_LOG + 4194304;
    const size_t OFF_MISC= OFF_A + SZ_A;                 // 262,144 f
    const size_t OFF_V   = OFF_MISC + 262144;
    const size_t OFF_GT  = OFF_V + 393216;
    const size_t OFF_SM  = OFF_GT + (G ? 589824 : 393216);

    float*          q0f    = ws + OFF_A;                               // !G
    unsigned short* qh     = (unsigned short*)(ws + OFF_A);            // G
    unsigned short* qm     = qh + (size_t)NB*NN*NC;
    unsigned short* ql     = qm + (size_t)NB*NN*NC;
    float*          W2     = ws + OFF_MISC;              // early life [0,147456)
    int*            knn    = (int*)(ws + OFF_MISC + 147456);
    float*          occ_part = ws + OFF_MISC + 163840;
    float*          vmat   = ws + OFF_V;
    float*          GtF    = ws + OFF_GT;                              // !G
    unsigned short* gh     = (unsigned short*)(ws + OFF_GT);           // G
    unsigned short* gm     = gh + (size_t)NB*NK*NC;
    unsigned short* gl     = gm + (size_t)NB*NK*NC;
    float*          Lsum   = ws + OFF_SM;
    float*          lpart  = ws + OFF_SM + 16;           // 256 loss partials

    float* out      = (float*)d_out;
    float* out_s0   = out;
    float* out_mu0  = out      + (size_t)NB*NN*NC;
    float* out_Sig0 = out_mu0  + (size_t)NB*NN*3;
    float* out_Bl   = out_Sig0 + (size_t)NB*NN*9;
    float* out_occn = out_Bl   + (size_t)NB*NN*NR;
    float* out_loss = out_occn + (size_t)NB*NK;

    (void)in_sizes; (void)n_in; (void)out_size;

    k_pre<<<38, 256, 0, stream>>>(node_mask, Wk, Wq, Lsum, W2);
    if (G) k_mid<true ><<<2496, 256, 0, stream>>>(s_parent, Wv, W2, res_idx, node_mask, Bm, ln_g, ln_b,
                                                  Lsum, mu_parent, Sig_parent, mask_par,
                                                  vmat, GtF, gh, gm, gl, q0f, qh, qm, ql, knn, occ_part);
    else   k_mid<false><<<2496, 256, 0, stream>>>(s_parent, Wv, W2, res_idx, node_mask, Bm, ln_g, ln_b,
                                                  Lsum, mu_parent, Sig_parent, mask_par,
                                                  vmat, GtF, gh, gm, gl, q0f, qh, qm, ql, knn, occ_part);
    if (G) k_fused<true ><<<256, 256, 0, stream>>>(q0f, qh, qm, ql, GtF, gh, gm, gl, mask_par,
                                                   vmat, mu_parent, Sig_parent, node_mask, knn,
                                                   out_s0, out_mu0, out_Sig0, out_Bl, occ_part, lpart);
    else   k_fused<false><<<256, 256, 0, stream>>>(q0f, qh, qm, ql, GtF, gh, gm, gl, mask_par,
                                                   vmat, mu_parent, Sig_parent, node_mask, knn,
                                                   out_s0, out_mu0, out_Sig0, out_Bl, occ_part, lpart);
    k_finalize<<<2, 512, 0, stream>>>(occ_part, Lsum, lpart, out_occn, out_loss);
}

// Round 13
// 101.655 us; speedup vs baseline: 1.1646x; 1.1646x over previous
//
#include <hip/hip_runtime.h>
#include <math.h>

#define NB 2
#define NN 4096
#define NK 512
#define NC 384
#define NR 16
#define NSLICE 64

static constexpr float INV_SQRT_C = 0.051031036307982884f; // 1/sqrt(384)
static constexpr float TWO_PI     = 6.283185307179586f;
static constexpr float F_JITTER   = 1e-4f;

typedef __attribute__((ext_vector_type(8))) short short8;
typedef __attribute__((ext_vector_type(4))) float f32x4;
typedef __attribute__((ext_vector_type(4))) unsigned short us4;
typedef __attribute__((ext_vector_type(8))) unsigned short us8;

__device__ __forceinline__ void split3(float x, unsigned short& h, unsigned short& m_, unsigned short& l_) {
    unsigned int xi = __float_as_uint(x);
    unsigned int uh = (xi + 0x7fffu + ((xi >> 16) & 1u)) >> 16;
    float fh = __uint_as_float(uh << 16);
    float r  = x - fh;
    unsigned int ri = __float_as_uint(r);
    unsigned int um = (ri + 0x7fffu + ((ri >> 16) & 1u)) >> 16;
    float fm = __uint_as_float(um << 16);
    float r2 = r - fm;
    unsigned int r2i = __float_as_uint(r2);
    unsigned int ul = (r2i + 0x7fffu + ((r2i >> 16) & 1u)) >> 16;
    h = (unsigned short)uh; m_ = (unsigned short)um; l_ = (unsigned short)ul;
}

// ======== launch 1: blocks 0..1 masksum | 2..37 W2 = Wk @ Wq^T | 38..39 pack P ========
__global__ __launch_bounds__(256) void k_pre(const float* __restrict__ node_mask,
                                             const float* __restrict__ Wk,
                                             const float* __restrict__ Wq,
                                             const float* __restrict__ mu,
                                             const float* __restrict__ Sg,
                                             const float* __restrict__ maskp,
                                             float* __restrict__ Lsum,
                                             float* __restrict__ W2,
                                             float* __restrict__ Pk) {
    __shared__ float red[256];
    __shared__ float As[16][68];
    __shared__ float Ws[16][68];
    int bid = blockIdx.x, t = threadIdx.x;
    if (bid < 2) {
        int b = bid;
        float s = 0.f;
        for (int n = t; n < NN; n += 256) s += node_mask[b*NN + n];
        red[t] = s; __syncthreads();
        for (int w = 128; w > 0; w >>= 1) { if (t < w) red[t] += red[t+w]; __syncthreads(); }
        if (t == 0) Lsum[b] = red[0];
        return;
    }
    if (bid >= 38) {                // ---- pack P[e] = {mu0,mu1,mu2,mask | S0,S1,S2,S4 | S5,S8,0,0} ----
        float4* P4 = (float4*)Pk;
        int e0 = ((bid - 38)*256 + t)*2;
        #pragma unroll
        for (int i = 0; i < 2; ++i) {
            int e = e0 + i;
            const float* mue = mu + (size_t)e*3;
            const float* Sge = Sg + (size_t)e*9;
            P4[e*3+0] = make_float4(mue[0], mue[1], mue[2], maskp[e]);
            P4[e*3+1] = make_float4(Sge[0], Sge[1], Sge[2], Sge[4]);
            P4[e*3+2] = make_float4(Sge[5], Sge[8], 0.f, 0.f);
        }
        return;
    }
    int gb = bid - 2;
    int rowbase = (gb % 6) * 64, colbase = (gb / 6) * 64;
    int tx = t & 15, ty = t >> 4;
    float acc[4][4] = {};
    for (int k0 = 0; k0 < NC; k0 += 16) {
        {
            int r = t >> 2, ja = (t & 3) << 2;
            float4 a4 = *(const float4*)(Wk + (size_t)(rowbase + r)*NC + k0 + ja);
            As[ja+0][r] = a4.x; As[ja+1][r] = a4.y; As[ja+2][r] = a4.z; As[ja+3][r] = a4.w;
        }
        {
            int r = t >> 2, jb = (t & 3) << 2;
            float4 b4 = *(const float4*)(Wq + (size_t)(colbase + r)*NC + k0 + jb);
            Ws[jb+0][r] = b4.x; Ws[jb+1][r] = b4.y; Ws[jb+2][r] = b4.z; Ws[jb+3][r] = b4.w;
        }
        __syncthreads();
        #pragma unroll
        for (int kk = 0; kk < 16; ++kk) {
            float4 av = *(const float4*)&As[kk][ty<<2];
            float4 wv = *(const float4*)&Ws[kk][tx<<2];
            float aa[4] = {av.x, av.y, av.z, av.w};
            float ww[4] = {wv.x, wv.y, wv.z, wv.w};
            #pragma unroll
            for (int i = 0; i < 4; ++i)
                #pragma unroll
                for (int j = 0; j < 4; ++j)
                    acc[i][j] += aa[i]*ww[j];
        }
        __syncthreads();
    }
    #pragma unroll
    for (int i = 0; i < 4; ++i) {
        float4 o = make_float4(acc[i][0], acc[i][1], acc[i][2], acc[i][3]);
        *(float4*)(W2 + (size_t)(rowbase + (ty<<2) + i)*NC + colbase + (tx<<2)) = o;
    }
}

// ======== launch 2: [0,192) dualz GEMM | [192,448) topk | [448,2496) q0 ========
template<bool SPLIT>
__global__ __launch_bounds__(256) void k_mid(const float* __restrict__ s_parent,
                                             const float* __restrict__ Wv,
                                             const float* __restrict__ W2,
                                             const int* __restrict__ res_idx,
                                             const float* __restrict__ node_mask,
                                             const float* __restrict__ Bm,
                                             const float* __restrict__ ln_g,
                                             const float* __restrict__ ln_b,
                                             const float* __restrict__ Lsum,
                                             const float* __restrict__ Pk,
                                             float* __restrict__ vmat,
                                             float* __restrict__ GtF,
                                             unsigned short* __restrict__ gh,
                                             unsigned short* __restrict__ gm,
                                             unsigned short* __restrict__ gl,
                                             float* __restrict__ q0f,
                                             unsigned short* __restrict__ qh,
                                             unsigned short* __restrict__ qm,
                                             unsigned short* __restrict__ ql,
                                             int* __restrict__ knn) {
    __shared__ float As[16][68];
    __shared__ float Ws[16][68];
    int bid = blockIdx.x, t = threadIdx.x;

    if (bid < 192) {                // ---- dual-z GEMM: z=0 vmat=s@Wv, z=1 Gt=s@W2 ----
        int z = bid / 96, rem = bid % 96;
        int rowbase = (rem % 16) * 64, colbase = (rem / 16) * 64;
        const float* W = z ? W2 : Wv;
        int tx = t & 15, ty = t >> 4;
        float acc[4][4] = {};
        for (int k0 = 0; k0 < NC; k0 += 16) {
            {
                int r = t >> 2, ja = (t & 3) << 2;
                float4 a4 = *(const float4*)(s_parent + (size_t)(rowbase + r)*NC + k0 + ja);
                As[ja+0][r] = a4.x; As[ja+1][r] = a4.y; As[ja+2][r] = a4.z; As[ja+3][r] = a4.w;
            }
            {
                int kr = t >> 4, jw = (t & 15) << 2;
                float4 w4 = *(const float4*)(W + (size_t)(k0 + kr)*NC + colbase + jw);
                *(float4*)&Ws[kr][jw] = w4;
            }
            __syncthreads();
            #pragma unroll
            for (int kk = 0; kk < 16; ++kk) {
                float4 av = *(const float4*)&As[kk][ty<<2];
                float4 wv = *(const float4*)&Ws[kk][tx<<2];
                float aa[4] = {av.x, av.y, av.z, av.w};
                float ww[4] = {wv.x, wv.y, wv.z, wv.w};
                #pragma unroll
                for (int i = 0; i < 4; ++i)
                    #pragma unroll
                    for (int j = 0; j < 4; ++j)
                        acc[i][j] += aa[i]*ww[j];
            }
            __syncthreads();
        }
        #pragma unroll
        for (int i = 0; i < 4; ++i) {
            size_t ro = (size_t)(rowbase + (ty<<2) + i)*NC + colbase + (tx<<2);
            if (z == 0) {
                *(float4*)(vmat + ro) = make_float4(acc[i][0], acc[i][1], acc[i][2], acc[i][3]);
            } else if constexpr (SPLIT) {
                us4 vh, vm, vl;
                #pragma unroll
                for (int j = 0; j < 4; ++j) {
                    unsigned short h, mm, ll;
                    split3(acc[i][j], h, mm, ll);
                    vh[j] = h; vm[j] = mm; vl[j] = ll;
                }
                *(us4*)(gh + ro) = vh; *(us4*)(gm + ro) = vm; *(us4*)(gl + ro) = vl;
            } else {
                *(float4*)(GtF + ro) = make_float4(acc[i][0], acc[i][1], acc[i][2], acc[i][3]);
            }
        }
        return;
    }

    if (bid < 448) {                // ---- topk: one 64-lane wave per row, packed gathers ----
        int wv_ = t >> 6, lane = t & 63;
        int tb = ((bid - 192) << 2) + wv_;
        int b = tb >> 9, i = tb & 511;
        const float4* P4 = (const float4*)Pk;
        int gi = b*NK + i;
        float4 i0 = P4[gi*3+0], i1 = P4[gi*3+1], i2 = P4[gi*3+2];
        float mi0 = i0.x, mi1 = i0.y, mi2 = i0.z, mski = i0.w;
        float S0 = i1.x, S1 = i1.y, S2 = i1.z, S4 = i1.w, S5 = i2.x, S8 = i2.y;
        float cand[8];
        #pragma unroll
        for (int h = 0; h < 8; ++h) {
            int jj = b*NK + lane + (h << 6);
            float4 j0_ = P4[jj*3+0], j1_ = P4[jj*3+1], j2_ = P4[jj*3+2];
            float d0 = mi0-j0_.x, d1 = mi1-j0_.y, d2 = mi2-j0_.z;
            float a00 = S0+j1_.x+1e-6f, a01 = S1+j1_.y,       a02 = S2+j1_.z;
            float a11 = S4+j1_.w+1e-6f, a12 = S5+j2_.x,       a22 = S8+j2_.y+1e-6f;
            float c00 = a11*a22 - a12*a12;
            float c01 = a02*a12 - a01*a22;
            float c02 = a01*a12 - a02*a11;
            float c11 = a00*a22 - a02*a02;
            float c12 = a01*a02 - a00*a12;
            float c22 = a00*a11 - a01*a01;
            float det = a00*c00 + a01*c01 + a02*c02;
            float t0 = c00*d0 + c01*d1 + c02*d2;
            float t1 = c01*d0 + c11*d1 + c12*d2;
            float t2 = c02*d0 + c12*d1 + c22*d2;
            float maha = (d0*t0 + d1*t1 + d2*t2) / det;
            float score = -0.5f*(maha + logf(det));
            cand[h] = (mski*j0_.w < 0.5f) ? -1e9f : score;
        }
        for (int it = 0; it < NR; ++it) {
            float bv = cand[0]; int bh = 0;
            #pragma unroll
            for (int h = 1; h < 8; ++h)
                if (cand[h] > bv) { bv = cand[h]; bh = h; }
            int bi = lane + (bh << 6);
            #pragma unroll
            for (int off = 32; off > 0; off >>= 1) {
                float v2 = __shfl_xor(bv, off);
                int   i2_ = __shfl_xor(bi, off);
                if (v2 > bv || (v2 == bv && i2_ < bi)) { bv = v2; bi = i2_; }
            }
            if (lane == 0) knn[((size_t)(b*NK + i))*NR + it] = bi;
            if ((bi & 63) == lane) {
                int s = bi >> 6;
                #pragma unroll
                for (int h = 0; h < 8; ++h)
                    if (h == s) cand[h] = -INFINITY;
            }
        }
        return;
    }

    // ---- q0: fourier emb + layernorm, wave-per-row ----
    int q0b = bid - 448;
    int w = t >> 6, l = t & 63;
    int row = (q0b << 2) + w;
    int b = row >> 12;
    float m = node_mask[row];
    float Lb = fmaxf(Lsum[b], 1.0f);
    float denom = fmaxf(Lb - 1.0f, 1.0f);
    int ri = res_idx[row];
    ri = ri < 0 ? 0 : (ri > 4095 ? 4095 : ri);
    float pos = fminf(fmaxf((float)ri / denom, 0.f), 1.f);
    float v[6];
    #pragma unroll
    for (int j = 0; j < 3; ++j) {
        float pr = TWO_PI * pos * Bm[l + (j << 6)];
        v[j]   = cosf(pr) * m;
        v[j+3] = sinf(pr) * m;
    }
    float sum = v[0]+v[1]+v[2]+v[3]+v[4]+v[5];
    #pragma unroll
    for (int off = 32; off > 0; off >>= 1) sum += __shfl_xor(sum, off);
    float mean = sum * (1.0f/NC);
    float sq = 0.f;
    #pragma unroll
    for (int j = 0; j < 6; ++j) { v[j] -= mean; sq += v[j]*v[j]; }
    #pragma unroll
    for (int off = 32; off > 0; off >>= 1) sq += __shfl_xor(sq, off);
    float var = sq * (1.0f/NC);
    float inv = 1.0f / sqrtf(var + 1e-5f);
    #pragma unroll
    for (int j = 0; j < 6; ++j) {
        int p = l + (j << 6);
        float val = v[j]*inv*ln_g[p] + ln_b[p];
        size_t o = (size_t)row*NC + p;
        if constexpr (SPLIT) {
            unsigned short h, mm, ll;
            split3(val, h, mm, ll);
            qh[o] = h; qm[o] = mm; ql[o] = ll;
        } else {
            q0f[o] = val;
        }
    }
}

// ======== launch 3: logits = q0 @ Gt^T via MFMA 3-split (6 passes) + argmax partials ========
template<bool SPLIT>
__global__ __launch_bounds__(256) void k_logits_mfma(const float* __restrict__ q0f,
                                                     const unsigned short* __restrict__ qh,
                                                     const unsigned short* __restrict__ qm,
                                                     const unsigned short* __restrict__ ql,
                                                     const float* __restrict__ GtF,
                                                     const unsigned short* __restrict__ gh,
                                                     const unsigned short* __restrict__ gm,
                                                     const unsigned short* __restrict__ gl,
                                                     const float* __restrict__ maskp,
                                                     float* __restrict__ logits,
                                                     float* __restrict__ pmaxv,
                                                     int*   __restrict__ pmaxi,
                                                     float* __restrict__ occ_part) {
    int bid = blockIdx.x;
    {   // zero occ_part [NSLICE][NB*NK] = 65536 floats across 512x256 threads
        int gid = bid * 256 + threadIdx.x;
        if (gid < NSLICE*NB*NK) occ_part[gid] = 0.f;
    }
    int wg = (bid & 7) * 64 + (bid >> 3);      // XCD-chunked swizzle (512 = 8*64)
    int b  = wg >> 8;
    int r8 = (wg >> 3) & 31;
    int cb = wg & 7;
    int rowbase = r8 << 7;
    int colbase = cb << 6;

    __shared__ __align__(16) unsigned short Ah[128][40];
    __shared__ __align__(16) unsigned short Am[128][40];
    __shared__ __align__(16) unsigned short Al[128][40];
    __shared__ __align__(16) unsigned short Bh[64][40];
    __shared__ __align__(16) unsigned short Bm2[64][40];
    __shared__ __align__(16) unsigned short Bl[64][40];
    __shared__ float rmv[128][2];
    __shared__ int   rmi[128][2];

    int t = threadIdx.x;
    int lane = t & 63, wv = t >> 6;
    int wr = wv >> 1, wc = wv & 1;
    int a = lane & 15, g = lane >> 4;

    size_t arow0 = (size_t)(b << 12) + rowbase;
    size_t brow0 = (size_t)(b << 9) + colbase;

    f32x4 acc[4][2];
    #pragma unroll
    for (int i = 0; i < 4; ++i)
        #pragma unroll
        for (int j = 0; j < 2; ++j)
            acc[i][j] = (f32x4){0.f, 0.f, 0.f, 0.f};

    for (int k0 = 0; k0 < NC; k0 += 32) {
        __syncthreads();
        if constexpr (SPLIT) {
            #pragma unroll
            for (int i = 0; i < 2; ++i) {       // A: 128 rows x 4 us8-segs (16B loads)
                int id = i*256 + t;
                int row = id >> 2, s2 = id & 3;
                size_t go = (arow0 + row)*NC + k0 + (s2 << 3);
                *(us8*)&Ah[row][s2 << 3] = *(const us8*)(qh + go);
                *(us8*)&Am[row][s2 << 3] = *(const us8*)(qm + go);
                *(us8*)&Al[row][s2 << 3] = *(const us8*)(ql + go);
            }
            {                                   // B: 64 rows x 4 us8-segs = 256 tasks
                int row = t >> 2, s2 = t & 3;
                size_t go = (brow0 + row)*NC + k0 + (s2 << 3);
                *(us8*)&Bh[row][s2 << 3]  = *(const us8*)(gh + go);
                *(us8*)&Bm2[row][s2 << 3] = *(const us8*)(gm + go);
                *(us8*)&Bl[row][s2 << 3]  = *(const us8*)(gl + go);
            }
        } else {
            #pragma unroll
            for (int i = 0; i < 4; ++i) {
                int id = i*256 + t;
                int row = id >> 3, seg = id & 7;
                float4 v = *(const float4*)(q0f + (arow0 + row)*NC + k0 + (seg << 2));
                unsigned short h0,m0,l0,h1,m1,l1,h2,m2,l2,h3,m3,l3;
                split3(v.x, h0, m0, l0); split3(v.y, h1, m1, l1);
                split3(v.z, h2, m2, l2); split3(v.w, h3, m3, l3);
                *(us4*)&Ah[row][seg << 2] = (us4){h0, h1, h2, h3};
                *(us4*)&Am[row][seg << 2] = (us4){m0, m1, m2, m3};
                *(us4*)&Al[row][seg << 2] = (us4){l0, l1, l2, l3};
            }
            #pragma unroll
            for (int i = 0; i < 2; ++i) {
                int id = i*256 + t;
                int row = id >> 3, seg = id & 7;
                float4 v = *(const float4*)(GtF + (brow0 + row)*NC + k0 + (seg << 2));
                unsigned short h0,m0,l0,h1,m1,l1,h2,m2,l2,h3,m3,l3;
                split3(v.x, h0, m0, l0); split3(v.y, h1, m1, l1);
                split3(v.z, h2, m2, l2); split3(v.w, h3, m3, l3);
                *(us4*)&Bh[row][seg << 2]  = (us4){h0, h1, h2, h3};
                *(us4*)&Bm2[row][seg << 2] = (us4){m0, m1, m2, m3};
                *(us4*)&Bl[row][seg << 2]  = (us4){l0, l1, l2, l3};
            }
        }
        __syncthreads();
        short8 afh[4], afm[4], afl[4];
        #pragma unroll
        for (int fr = 0; fr < 4; ++fr) {
            int r = (wr << 6) + (fr << 4) + a;
            afh[fr] = *(const short8*)&Ah[r][g << 3];
            afm[fr] = *(const short8*)&Am[r][g << 3];
            afl[fr] = *(const short8*)&Al[r][g << 3];
        }
        #pragma unroll
        for (int fc = 0; fc < 2; ++fc) {
            int c = (wc << 5) + (fc << 4) + a;
            short8 bh = *(const short8*)&Bh[c][g << 3];
            short8 bm = *(const short8*)&Bm2[c][g << 3];
            short8 bl = *(const short8*)&Bl[c][g << 3];
            #pragma unroll
            for (int fr = 0; fr < 4; ++fr) {
                acc[fr][fc] = __builtin_amdgcn_mfma_f32_16x16x32_bf16(afh[fr], bh, acc[fr][fc], 0, 0, 0);
                acc[fr][fc] = __builtin_amdgcn_mfma_f32_16x16x32_bf16(afh[fr], bm, acc[fr][fc], 0, 0, 0);
                acc[fr][fc] = __builtin_amdgcn_mfma_f32_16x16x32_bf16(afm[fr], bh, acc[fr][fc], 0, 0, 0);
                acc[fr][fc] = __builtin_amdgcn_mfma_f32_16x16x32_bf16(afh[fr], bl, acc[fr][fc], 0, 0, 0);
                acc[fr][fc] = __builtin_amdgcn_mfma_f32_16x16x32_bf16(afl[fr], bh, acc[fr][fc], 0, 0, 0);
                acc[fr][fc] = __builtin_amdgcn_mfma_f32_16x16x32_bf16(afm[fr], bm, acc[fr][fc], 0, 0, 0);
            }
        }
    }
    float mk[2];
    #pragma unroll
    for (int fc = 0; fc < 2; ++fc)
        mk[fc] = (maskp[(b << 9) + colbase + (wc << 5) + (fc << 4) + a] - 1.0f) * 1e9f;
    int colg0 = colbase + (wc << 5) + a;
    #pragma unroll
    for (int fr = 0; fr < 4; ++fr) {
        #pragma unroll
        for (int reg = 0; reg < 4; ++reg) {
            int rloc = (wr << 6) + (fr << 4) + (g << 2) + reg;
            size_t rowg = (size_t)(b << 12) + rowbase + rloc;
            float v0 = acc[fr][0][reg] * INV_SQRT_C;
            float v1 = acc[fr][1][reg] * INV_SQRT_C;
            logits[rowg * NK + colg0]      = v0;
            logits[rowg * NK + colg0 + 16] = v1;
            float bv = v0 + mk[0]; int bc = colg0;
            float w1 = v1 + mk[1];
            if (w1 > bv) { bv = w1; bc = colg0 + 16; }
            #pragma unroll
            for (int off = 1; off < 16; off <<= 1) {
                float v2 = __shfl_xor(bv, off);
                int   c2 = __shfl_xor(bc, off);
                if (v2 > bv || (v2 == bv && c2 < bc)) { bv = v2; bc = c2; }
            }
            if (a == 0) { rmv[rloc][wc] = bv; rmi[rloc][wc] = bc; }
        }
    }
    __syncthreads();
    if (t < 128) {
        float v0 = rmv[t][0], v1 = rmv[t][1];
        int   c0 = rmi[t][0], c1 = rmi[t][1];
        float bv = v0; int bc = c0;
        if (v1 > bv) { bv = v1; bc = c1; }
        pmaxv[(((size_t)(b << 3) + cb) << 12) + rowbase + t] = bv;
        pmaxi[(((size_t)(b << 3) + cb) << 12) + rowbase + t] = bc;
    }
}

// ======== launch 4: gathered attention epilogue — 8 rows/block, packed gathers ========
__global__ __launch_bounds__(256) void k_final(const float* __restrict__ logits,
                                               const float* __restrict__ vmat,
                                               const float* __restrict__ Pk,
                                               const float* __restrict__ node_mask,
                                               const float* __restrict__ pmaxv,
                                               const int*   __restrict__ pmaxi,
                                               const int* __restrict__ knn,
                                               float* __restrict__ out_s0,
                                               float* __restrict__ out_mu0,
                                               float* __restrict__ out_Sig0,
                                               float* __restrict__ out_Bl,
                                               float* __restrict__ occ_part,
                                               float* __restrict__ loss_part) {
    int t = threadIdx.x;
    int rowbase = blockIdx.x << 3;          // 8 rows per block
    int b = rowbase >> 12;
    int l  = t & 63;
    int sub = l >> 4, ll = l & 15;
    int wv = t >> 6;
    int r = (wv << 1) + sub;
    bool act = (sub < 2);
    int grow = rowbase + (act ? r : 0);
    __shared__ float wl[8][17];
    __shared__ int   pidx[8][17];
    __shared__ float lred[8];
    __shared__ float msk[8];
    __shared__ int   j0s[8];

    if (t < 8) {                            // combine 8 argmax partials -> j0
        int rowb = (rowbase & 4095) + t;
        float bv = -INFINITY; int bj = 0;
        #pragma unroll
        for (int cbk = 0; cbk < 8; ++cbk) {
            size_t idx = (((size_t)(b << 3) + cbk) << 12) + rowb;
            float v = pmaxv[idx];
            if (v > bv) { bv = v; bj = pmaxi[idx]; }
        }
        j0s[t] = bj;
    }
    __syncthreads();

    if (act) {
        float m = node_mask[grow];
        int p = knn[((size_t)(b*NK + j0s[r]))*NR + ll];
        float v = logits[(size_t)grow*NK + p];
        float mx = v;
        #pragma unroll
        for (int off = 8; off > 0; off >>= 1) mx = fmaxf(mx, __shfl_xor(mx, off));
        float e = expf(v - mx);
        float sme = e;
        #pragma unroll
        for (int off = 8; off > 0; off >>= 1) sme += __shfl_xor(sme, off);
        float w = e / sme;
        wl[r][ll] = w;
        pidx[r][ll] = p;
        out_Bl[(size_t)grow*NR + ll] = w;

        const float4* P4 = (const float4*)Pk;
        int gp = b*NK + p;
        float4 x0 = P4[gp*3+0], x1 = P4[gp*3+1], x2 = P4[gp*3+2];
        float mr0 = x0.x, mr1 = x0.y, mr2 = x0.z;
        float m0 = w*mr0, m1 = w*mr1, m2 = w*mr2;
        #pragma unroll
        for (int off = 8; off > 0; off >>= 1) {
            m0 += __shfl_xor(m0, off); m1 += __shfl_xor(m1, off); m2 += __shfl_xor(m2, off);
        }
        float d0 = mr0-m0, d1 = mr1-m1, d2 = mr2-m2;
        float a00 = x1.x, a01 = x1.y, a02 = x1.z;
        float a11 = x1.w, a12 = x2.x, a22 = x2.y;
        float p00 = w*(a00 + d0*d0), p01 = w*(a01 + d0*d1), p02 = w*(a02 + d0*d2);
        float p11 = w*(a11 + d1*d1), p12 = w*(a12 + d1*d2), p22 = w*(a22 + d2*d2);
        #pragma unroll
        for (int off = 8; off > 0; off >>= 1) {
            p00 += __shfl_xor(p00, off); p01 += __shfl_xor(p01, off); p02 += __shfl_xor(p02, off);
            p11 += __shfl_xor(p11, off); p12 += __shfl_xor(p12, off); p22 += __shfl_xor(p22, off);
        }
        float c00 = a11*a22 - a12*a12;
        float c01 = a02*a12 - a01*a22;
        float c02 = a01*a12 - a02*a11;
        float c11 = a00*a22 - a02*a02;
        float c12 = a01*a02 - a00*a12;
        float c22 = a00*a11 - a01*a01;
        float det = a00*c00 + a01*c01 + a02*c02;
        float t0 = c00*d0 + c01*d1 + c02*d2;
        float t1 = c01*d0 + c11*d1 + c12*d2;
        float t2 = c02*d0 + c12*d1 + c22*d2;
        float maha = (d0*t0 + d1*t1 + d2*t2) / det;
        float score = -0.5f*(maha + logf(det));
        float lp = w*score;
        #pragma unroll
        for (int off = 8; off > 0; off >>= 1) lp += __shfl_xor(lp, off);
        if (ll == 0) {
            out_mu0[(size_t)grow*3+0] = m0;
            out_mu0[(size_t)grow*3+1] = m1;
            out_mu0[(size_t)grow*3+2] = m2;
            float* o = out_Sig0 + (size_t)grow*9;
            o[0]=p00+F_JITTER; o[1]=p01;          o[2]=p02;
            o[3]=p01;          o[4]=p11+F_JITTER; o[5]=p12;
            o[6]=p02;          o[7]=p12;          o[8]=p22+F_JITTER;
            lred[r] = m*lp;
            msk[r] = m;
        }
        atomicAdd(&occ_part[(size_t)(blockIdx.x & (NSLICE-1))*(NB*NK) + b*NK + p], w*m);
    }
    __syncthreads();
    if (t == 0) {
        float s = 0.f;
        #pragma unroll
        for (int i = 0; i < 8; ++i) s += lred[i];
        loss_part[blockIdx.x] = s;
    }
    // PV: 8 rows x 96 float4 = 768 tasks over 256 threads (3 iters), coalesced
    const float4* vb = (const float4*)(vmat + (size_t)b*NK*NC);
    #pragma unroll
    for (int it = 0; it < 3; ++it) {
        int id = it*256 + t;
        int row = id / 96;
        int col = id - row*96;
        float4 acc4 = make_float4(0.f, 0.f, 0.f, 0.f);
        #pragma unroll
        for (int r2 = 0; r2 < NR; ++r2) {
            float ww = wl[row][r2];
            float4 vv = vb[(size_t)pidx[row][r2]*96 + col];
            acc4.x += ww*vv.x; acc4.y += ww*vv.y; acc4.z += ww*vv.z; acc4.w += ww*vv.w;
        }
        float mm = msk[row];
        acc4.x *= mm; acc4.y *= mm; acc4.z *= mm; acc4.w *= mm;
        ((float4*)(out_s0 + (size_t)(rowbase + row)*NC))[col] = acc4;
    }
}

// ======== launch 5: occ-slice reduce + normalize + loss (2 blocks) ========
__global__ __launch_bounds__(512) void k_finalize(const float* __restrict__ occ_part,
                                                  const float* __restrict__ Lsum,
                                                  const float* __restrict__ loss_part,
                                                  float* __restrict__ out_occn,
                                                  float* __restrict__ out_loss) {
    int b = blockIdx.x, t = threadIdx.x;
    __shared__ float red[512];
    float s = 0.f;
    for (int sl = 0; sl < NSLICE; ++sl) s += occ_part[(size_t)sl*(NB*NK) + b*NK + t];
    red[t] = s; __syncthreads();
    for (int w = 256; w > 0; w >>= 1) { if (t < w) red[t] += red[t+w]; __syncthreads(); }
    float tot = red[0];
    __syncthreads();
    out_occn[b*NK + t] = s / fmaxf(tot, 1e-9f);
    if (b == 0) {
        red[t] = loss_part[t] + loss_part[t + 512];       // 1024 partials
        __syncthreads();
        for (int w = 256; w > 0; w >>= 1) { if (t < w) red[t] += red[t+w]; __syncthreads(); }
        if (t == 0) {
            float dnm = fmaxf(Lsum[0] + Lsum[1], 1.0f);
            out_loss[0] = -(red[0] / dnm);
        }
    }
}

extern "C" void kernel_launch(void* const* d_in, const int* in_sizes, int n_in,
                              void* d_out, int out_size, void* d_ws, size_t ws_size,
                              hipStream_t stream) {
    const float* s_parent   = (const float*)d_in[0];
    const float* mu_parent  = (const float*)d_in[1];
    const float* Sig_parent = (const float*)d_in[2];
    const float* mask_par   = (const float*)d_in[3];
    const float* node_mask  = (const float*)d_in[4];
    const int*   res_idx    = (const int*)d_in[5];
    const float* Bm         = (const float*)d_in[6];
    const float* Wq         = (const float*)d_in[7];
    const float* Wk         = (const float*)d_in[8];
    const float* Wv         = (const float*)d_in[9];
    const float* ln_g       = (const float*)d_in[10];
    const float* ln_b       = (const float*)d_in[11];

    const bool G = (ws_size >= (43ull << 20));   // pre-split path; fallback = fp32+in-kernel split

    float* ws = (float*)d_ws;
    const size_t SZ_A    = G ? 4718592 : 3145728;        // q0 splits (3 bf16 planes) | q0 fp32
    const size_t OFF_LOG = 0;                            // logits 4,194,304 f
    const size_t OFF_A   = OFF_LOG + 4194304;
    const size_t OFF_MISC= OFF_A + SZ_A;                 // 262,144 f
    const size_t OFF_V   = OFF_MISC + 262144;            // vmat 393,216 f
    const size_t OFF_GT  = OFF_V + 393216;               // Gt: splits 589,824 f | fp32 393,216 f
    const size_t OFF_SM  = OFF_GT + (G ? 589824 : 393216);
    const size_t OFF_P   = OFF_SM + 16 + 1024;           // packed P: 12,288 f (16B-aligned)

    float*          logits = ws + OFF_LOG;
    float*          q0f    = ws + OFF_A;                               // !G
    unsigned short* qh     = (unsigned short*)(ws + OFF_A);            // G
    unsigned short* qm     = qh + (size_t)NB*NN*NC;
    unsigned short* ql     = qm + (size_t)NB*NN*NC;
    // MISC region lifetimes: W2 [0,147456) early (launch1-2);
    // pmaxv/pmaxi [0,131072) from launch3; knn [147456,163840) from launch2 (disjoint from W2);
    // occ_part [163840,229376) launch3+.
    float*          W2     = ws + OFF_MISC;
    float*          pmaxv  = ws + OFF_MISC;
    int*            pmaxi  = (int*)(ws + OFF_MISC + 65536);
    int*            knn    = (int*)(ws + OFF_MISC + 147456);
    float*          occ_part = ws + OFF_MISC + 163840;
    float*          vmat   = ws + OFF_V;
    float*          GtF    = ws + OFF_GT;                              // !G
    unsigned short* gh     = (unsigned short*)(ws + OFF_GT);           // G
    unsigned short* gm     = gh + (size_t)NB*NK*NC;
    unsigned short* gl     = gm + (size_t)NB*NK*NC;
    float*          Lsum   = ws + OFF_SM;
    float*          lpart  = ws + OFF_SM + 16;           // 1024 loss partials
    float*          Pk     = ws + OFF_P;                 // packed {mu,mask|Sig} table

    float* out      = (float*)d_out;
    float* out_s0   = out;
    float* out_mu0  = out      + (size_t)NB*NN*NC;
    float* out_Sig0 = out_mu0  + (size_t)NB*NN*3;
    float* out_Bl   = out_Sig0 + (size_t)NB*NN*9;
    float* out_occn = out_Bl   + (size_t)NB*NN*NR;
    float* out_loss = out_occn + (size_t)NB*NK;

    (void)in_sizes; (void)n_in; (void)out_size;

    k_pre<<<40, 256, 0, stream>>>(node_mask, Wk, Wq, mu_parent, Sig_parent, mask_par,
                                  Lsum, W2, Pk);
    if (G) k_mid<true ><<<2496, 256, 0, stream>>>(s_parent, Wv, W2, res_idx, node_mask, Bm, ln_g, ln_b,
                                                  Lsum, Pk, vmat, GtF, gh, gm, gl, q0f, qh, qm, ql, knn);
    else   k_mid<false><<<2496, 256, 0, stream>>>(s_parent, Wv, W2, res_idx, node_mask, Bm, ln_g, ln_b,
                                                  Lsum, Pk, vmat, GtF, gh, gm, gl, q0f, qh, qm, ql, knn);
    if (G) k_logits_mfma<true ><<<512, 256, 0, stream>>>(q0f, qh, qm, ql, GtF, gh, gm, gl,
                                                         mask_par, logits, pmaxv, pmaxi, occ_part);
    else   k_logits_mfma<false><<<512, 256, 0, stream>>>(q0f, qh, qm, ql, GtF, gh, gm, gl,
                                                         mask_par, logits, pmaxv, pmaxi, occ_part);
    k_final<<<(NB*NN)/8, 256, 0, stream>>>(logits, vmat, Pk, node_mask,
                                           pmaxv, pmaxi, knn, out_s0, out_mu0, out_Sig0,
                                           out_Bl, occ_part, lpart);
    k_finalize<<<2, 512, 0, stream>>>(occ_part, Lsum, lpart, out_occn, out_loss);
}